// Round 1
// baseline (532.489 us; speedup 1.0000x reference)
//
#include <hip/hip_runtime.h>
#include <math.h>

// Problem constants (from reference): B=32, C=D=64, H=W=64, K=1024
constexpr int K_CODES = 1024;
constexpr int D_DIM   = 64;
constexpr int HW      = 64 * 64;          // 4096
constexpr int NPOS    = 32 * HW;          // 131072 positions
constexpr int CHW     = D_DIM * HW;       // 262144 (per-batch stride)

// ws layout (floats): [0..1023] c2 (codebook squared norms), [1024..2047] histogram
// prep kernel: compute c2[k] and zero the histogram (ws is poisoned each call)
__global__ void vq_prep(const float* __restrict__ cb, float* __restrict__ ws) {
    int k = blockIdx.x * blockDim.x + threadIdx.x;
    if (k < K_CODES) {
        const float4* row = reinterpret_cast<const float4*>(cb + k * D_DIM);
        float s0 = 0.f, s1 = 0.f, s2 = 0.f, s3 = 0.f;
#pragma unroll
        for (int i = 0; i < 16; ++i) {
            float4 v = row[i];
            s0 = fmaf(v.x, v.x, s0);
            s1 = fmaf(v.y, v.y, s1);
            s2 = fmaf(v.z, v.z, s2);
            s3 = fmaf(v.w, v.w, s3);
        }
        ws[k] = (s0 + s1) + (s2 + s3);
        ws[K_CODES + k] = 0.0f;
    }
}

// main kernel: one thread per spatial position
__global__ __launch_bounds__(256) void vq_main(
    const float* __restrict__ in, const float* __restrict__ cb,
    float* __restrict__ out, float* __restrict__ ws) {
    const float* __restrict__ c2 = ws;
    float* hist = ws + K_CODES;

    int n  = blockIdx.x * 256 + threadIdx.x;   // n = b*HW + hw
    int b  = n >> 12;                          // / 4096
    int hw = n & 4095;
    const float* xb = in + (size_t)b * CHW + hw;

    // load x[c] (strided gather, coalesced across lanes per c)
    float x[D_DIM];
#pragma unroll
    for (int c = 0; c < D_DIM; ++c) x[c] = xb[(size_t)c * HW];

    // x2 = sum x^2 (4 partials)
    float s0 = 0.f, s1 = 0.f, s2 = 0.f, s3 = 0.f;
#pragma unroll
    for (int c = 0; c < D_DIM; c += 4) {
        s0 = fmaf(x[c + 0], x[c + 0], s0);
        s1 = fmaf(x[c + 1], x[c + 1], s1);
        s2 = fmaf(x[c + 2], x[c + 2], s2);
        s3 = fmaf(x[c + 3], x[c + 3], s3);
    }
    float x2 = (s0 + s1) + (s2 + s3);

    float best = INFINITY;
    int   bidx = 0;
    for (int k = 0; k < K_CODES; ++k) {
        // wave-uniform address: broadcast load (L1/L2), possibly scalarized
        const float4* crow = reinterpret_cast<const float4*>(cb + k * D_DIM);
        float d0 = 0.f, d1 = 0.f, d2 = 0.f, d3 = 0.f;
#pragma unroll
        for (int i = 0; i < 16; ++i) {
            float4 v = crow[i];
            d0 = fmaf(x[4 * i + 0], v.x, d0);
            d1 = fmaf(x[4 * i + 1], v.y, d1);
            d2 = fmaf(x[4 * i + 2], v.z, d2);
            d3 = fmaf(x[4 * i + 3], v.w, d3);
        }
        float dot  = (d0 + d1) + (d2 + d3);
        // replicate reference association: (x2 - 2*dot) + c2
        float dist = (x2 - 2.0f * dot) + c2[k];
        bool m = dist < best;          // strict < keeps first index on ties
        best = m ? dist : best;
        bidx = m ? k : bidx;
    }

    // quantized = x + (q - x), written NCHW (coalesced per channel)
    float* ob = out + (size_t)b * CHW + hw;
    const float* __restrict__ q = cb + bidx * D_DIM;
#pragma unroll
    for (int c = 0; c < D_DIM; ++c) {
        float qc = q[c];
        ob[(size_t)c * HW] = x[c] + (qc - x[c]);
    }

    atomicAdd(&hist[bidx], 1.0f);
}

// perplexity: one block, 1024 threads (16 waves)
__global__ void vq_ppl(const float* __restrict__ ws, float* __restrict__ outp) {
    __shared__ float red[16];
    int t = threadIdx.x;
    float e = ws[K_CODES + t] * (1.0f / (float)NPOS);
    float term = e * logf(e + 1e-10f);
    // wave64 reduction
#pragma unroll
    for (int off = 32; off > 0; off >>= 1)
        term += __shfl_down(term, off, 64);
    int lane = t & 63, wid = t >> 6;
    if (lane == 0) red[wid] = term;
    __syncthreads();
    if (t == 0) {
        float s = 0.f;
#pragma unroll
        for (int i = 0; i < 16; ++i) s += red[i];
        *outp = expf(-s);
    }
}

extern "C" void kernel_launch(void* const* d_in, const int* in_sizes, int n_in,
                              void* d_out, int out_size, void* d_ws, size_t ws_size,
                              hipStream_t stream) {
    const float* in = (const float*)d_in[0];   // [32,64,64,64] fp32
    const float* cb = (const float*)d_in[1];   // [1024,64] fp32
    // d_in[2] = beta (unused in eval forward)
    float* out = (float*)d_out;                // quantized [8388608] + ppl [1]
    float* ws  = (float*)d_ws;                 // >= 8KB

    vq_prep<<<4, 256, 0, stream>>>(cb, ws);
    vq_main<<<NPOS / 256, 256, 0, stream>>>(in, cb, out, ws);
    vq_ppl<<<1, 1024, 0, stream>>>(ws, out + (size_t)8388608);
}